// Round 5
// baseline (129.965 us; speedup 1.0000x reference)
//
#include <hip/hip_runtime.h>

#define B_    16384
#define NZ_   64
#define ND_   8
#define SDIM_ 128
#define H_    512

typedef _Float16 f16;
typedef __attribute__((ext_vector_type(4))) _Float16 half4;
typedef __attribute__((ext_vector_type(8))) _Float16 half8;
typedef __attribute__((ext_vector_type(4))) float floatx4;

// swizzle byte-bits 4-6 with (row>>1)&7.  NOTE (r4 post-mortem): the residual
// SQ_LDS_BANK_CONFLICT ~2.1M is the inherent 2-lane/granule aliasing of wave64
// ds_read_b128 (free per m136) — do not chase it.
__device__ __forceinline__ int pswz(int row, int colbyte) {
    return (row * 1024 + colbyte) ^ (((row >> 1) & 7) << 4);
}

// ---------------- weight pack: [*,K,N] f32 -> fragment-tiled f16 ----------------
// packed ((nt*(K/32) + kt)*64 + lane)*8 + j == W[kt*32 + (lane>>4)*8 + j][nt*16 + (lane&15)]
__device__ __forceinline__ void tr_mat(float (*tb)[33], const float* __restrict__ s,
                                       f16* __restrict__ dd, int K, int N, int tl) {
    const int ntk = K >> 5;
    const int per = ntk * (N >> 5);
    const int bt  = tl / per;
    const int w   = tl - bt * per;
    s  += (size_t)bt * K * N;
    dd += (size_t)bt * K * N;
    const int k0 = (w % ntk) << 5, n0 = (w / ntk) << 5;
    const int tid = threadIdx.x;
    {
        const int nn = tid & 31, k4 = tid >> 5;
        #pragma unroll
        for (int p = 0; p < 4; p++)
            tb[k4 + p * 8][nn] = s[(size_t)(k0 + k4 + p * 8) * N + n0 + nn];
    }
    __syncthreads();
    {
        const int sub = tid >> 7, r = tid & 127;
        const int lane = r >> 1, jp = (r & 1) * 4;
        const int kb = lane >> 4, l15 = lane & 15;
        const size_t base = ((size_t)((n0 >> 4) + sub) * (K >> 5) + (k0 >> 5)) * 512
                          + lane * 8 + jp;
        half4 h;
        #pragma unroll
        for (int jj = 0; jj < 4; jj++)
            h[jj] = (f16)tb[kb * 8 + jp + jj][sub * 16 + l15];
        *(half4*)(dd + base) = h;
    }
}

__global__ __launch_bounds__(256) void tr_k(
    const float* W0, const float* W1, const float* W2, const float* W3,
    const float* U1, const float* U2, const float* U3, const float* Uo,
    f16* W0t, f16* W1t, f16* W2t, f16* W3t,
    f16* U1t, f16* U2t, f16* U3t, f16* Uot)
{
    __shared__ float tb[32][33];
    int tl = blockIdx.x;
    if (tl < 32)   { tr_mat(tb, W0, W0t, 64, 512, tl); return; }  tl -= 32;
    if (tl < 256)  { tr_mat(tb, W1, W1t, 512, 512, tl); return; } tl -= 256;
    if (tl < 256)  { tr_mat(tb, W2, W2t, 512, 512, tl); return; } tl -= 256;
    if (tl < 256)  { tr_mat(tb, W3, W3t, 512, 512, tl); return; } tl -= 256;
    if (tl < 2048) { tr_mat(tb, U1, U1t, 512, 512, tl); return; } tl -= 2048;
    if (tl < 2048) { tr_mat(tb, U2, U2t, 512, 512, tl); return; } tl -= 2048;
    if (tl < 2048) { tr_mat(tb, U3, U3t, 512, 512, tl); return; } tl -= 2048;
    tr_mat(tb, Uo, Uot, 512, 128, tl);
}
#define TR_BLOCKS 7456

// ---------------- domain sort ----------------
__global__ void misc_k(int* __restrict__ cnt, int* __restrict__ rowmap) {
    const int t = threadIdx.x;
    if (t < ND_) cnt[t] = 0;
    if (t < 128) rowmap[B_ + t] = 0;     // pad for last-domain tail tile
}

__global__ __launch_bounds__(256) void count_k(const int* __restrict__ y,
                                               int* __restrict__ cnt) {
    __shared__ int h[ND_];
    if (threadIdx.x < ND_) h[threadIdx.x] = 0;
    __syncthreads();
    atomicAdd(&h[y[blockIdx.x * 256 + threadIdx.x]], 1);   // grid covers B_ exactly
    __syncthreads();
    if (threadIdx.x < ND_) atomicAdd(&cnt[threadIdx.x], h[threadIdx.x]);
}

__global__ void prefix_k(const int* __restrict__ cnt, int* __restrict__ offs,
                         int* __restrict__ running) {
    if (threadIdx.x == 0) {
        int o = 0;
        offs[0] = 0;
        for (int d = 0; d < ND_; d++) { running[d] = o; o += cnt[d]; offs[d + 1] = o; }
    }
}

__global__ __launch_bounds__(256) void scatter_k(const int* __restrict__ y,
                                                 int* __restrict__ running,
                                                 int* __restrict__ rowmap) {
    __shared__ int h[ND_], base[ND_];
    if (threadIdx.x < ND_) h[threadIdx.x] = 0;
    __syncthreads();
    const int b = blockIdx.x * 256 + threadIdx.x;
    const int d = y[b];
    const int r = atomicAdd(&h[d], 1);
    __syncthreads();
    if (threadIdx.x < ND_) base[threadIdx.x] = atomicAdd(&running[threadIdx.x], h[threadIdx.x]);
    __syncthreads();
    rowmap[base[d] + r] = b;
}

// ---------------- one fused layer with rolling depth-3 cross-layer B prefetch ----------------
// Flat k-step counter across layers; ring b[4][4]; loads issued 3 steps ahead
// (incl. into the NEXT layer's weights wpn, hidden under epilogue+barrier).
// SB = flat-step base of this layer & 3.  NFN/KTN describe the next layer.
template<int MFRAG, int NFRAG, int KT, int NFN, int KTN, int SB, bool RELU, bool TOPANEL>
__device__ __forceinline__ void layer_f(
    char* lds, const half8* __restrict__ wp, const half8* __restrict__ wpn,
    const float* __restrict__ bias, half8 (&b)[4][4],
    float* __restrict__ outf, const int* __restrict__ rowmap, int row0, int vend)
{
    const int t = threadIdx.x;
    const int lane = t & 63, wid = t >> 6;
    const int l15 = lane & 15, kb = lane >> 4;

    int baseA[MFRAG];
    #pragma unroll
    for (int m = 0; m < MFRAG; m++)
        baseA[m] = (((m * 16 + l15) * 1024) + kb * 16) ^ (((l15 >> 1) & 7) << 4);

    half8 a[2][MFRAG];
    #pragma unroll
    for (int m = 0; m < MFRAG; m++) a[0][m] = *(const half8*)(lds + baseA[m]);

    floatx4 acc[MFRAG][NFRAG] = {};

    #pragma unroll
    for (int kt = 0; kt < KT; kt++) {
        const int cur = kt & 1;
        if (kt + 1 < KT) {                         // A prefetch, 1 step ahead
            #pragma unroll
            for (int m = 0; m < MFRAG; m++)
                a[cur ^ 1][m] = *(const half8*)(lds + (baseA[m] ^ ((kt + 1) << 6)));
        }
        if (kt + 3 < KT) {                         // B prefetch, 3 steps ahead
            #pragma unroll
            for (int n = 0; n < NFRAG; n++)
                b[(SB + kt + 3) & 3][n] = wp[((wid * NFRAG + n) * KT + kt + 3) * 64 + lane];
        } else if constexpr (NFN > 0) {            // cross into next layer (steps 0..2 of it)
            const int s2 = kt + 3 - KT;
            #pragma unroll
            for (int n = 0; n < NFN; n++)
                b[(SB + kt + 3) & 3][n] = wpn[((wid * NFN + n) * KTN + s2) * 64 + lane];
        }
        __builtin_amdgcn_s_setprio(1);
        #pragma unroll
        for (int m = 0; m < MFRAG; m++)
            #pragma unroll
            for (int n = 0; n < NFRAG; n++)
                acc[m][n] = __builtin_amdgcn_mfma_f32_16x16x32_f16(
                    a[cur][m], b[(SB + kt) & 3][n], acc[m][n], 0, 0, 0);
        __builtin_amdgcn_s_setprio(0);
    }

    __syncthreads();   // all waves done reading panel

    #pragma unroll
    for (int n = 0; n < NFRAG; n++) {
        const int col = wid * (NFRAG * 16) + n * 16 + l15;
        const float bb = bias[col];
        #pragma unroll
        for (int m = 0; m < MFRAG; m++) {
            #pragma unroll
            for (int e = 0; e < 4; e++) {
                const int row = m * 16 + kb * 4 + e;
                float v = acc[m][n][e] + bb;
                if constexpr (RELU) v = fmaxf(v, 0.0f);
                if constexpr (TOPANEL) {
                    *(f16*)(lds + pswz(row, col * 2)) = (f16)v;
                } else {
                    const int pr = row0 + row;
                    if (pr < vend) outf[(size_t)rowmap[pr] * SDIM_ + col] = v;
                }
            }
        }
    }
    if constexpr (TOPANEL) __syncthreads();   // panel is next layer's input
}

// ---------------- fused trunk: z -> 4 layers -> hT ----------------
__global__ __launch_bounds__(512, 2) void trunk_k(
    const float* __restrict__ z,
    const f16* __restrict__ W0p, const float* __restrict__ b0,
    const f16* __restrict__ W1p, const float* __restrict__ b1,
    const f16* __restrict__ W2p, const float* __restrict__ b2,
    const f16* __restrict__ W3p, const float* __restrict__ b3,
    f16* __restrict__ hT)
{
    extern __shared__ char lds[];
    const int t = threadIdx.x;
    const int row0 = blockIdx.x * 64;
    const int lane = t & 63, wid = t >> 6;

    const half8* w0 = (const half8*)W0p;
    const half8* w1 = (const half8*)W1p;
    const half8* w2 = (const half8*)W2p;
    const half8* w3 = (const half8*)W3p;

    half8 b[4][4];
    #pragma unroll
    for (int n = 0; n < 4; n++) {                  // flat steps 0,1 (w0 KT=2), 2 (w1 s0)
        b[0][n] = w0[((wid * 4 + n) * 2 + 0) * 64 + lane];
        b[1][n] = w0[((wid * 4 + n) * 2 + 1) * 64 + lane];
        b[2][n] = w1[((wid * 4 + n) * 16 + 0) * 64 + lane];
    }

    {   // fill panel with z rows (f32 -> f16), swizzled
        const int r = t >> 3, c = (t & 7) * 8;
        const float4 v0 = *(const float4*)(z + (size_t)(row0 + r) * NZ_ + c);
        const float4 v1 = *(const float4*)(z + (size_t)(row0 + r) * NZ_ + c + 4);
        half8 h = { (f16)v0.x, (f16)v0.y, (f16)v0.z, (f16)v0.w,
                    (f16)v1.x, (f16)v1.y, (f16)v1.z, (f16)v1.w };
        *(half8*)(lds + pswz(r, c * 2)) = h;
    }
    __syncthreads();

    // flat bases: 0, 2, 18, 34  ->  SB&3 = 0, 2, 2, 2
    layer_f<4, 4, 2,  4, 16, 0, true, true>(lds, w0, w1, b0, b, nullptr, nullptr, 0, 0);
    layer_f<4, 4, 16, 4, 16, 2, true, true>(lds, w1, w2, b1, b, nullptr, nullptr, 0, 0);
    layer_f<4, 4, 16, 4, 16, 2, true, true>(lds, w2, w3, b2, b, nullptr, nullptr, 0, 0);
    layer_f<4, 4, 16, 0, 16, 2, true, true>(lds, w3, w3, b3, b, nullptr, nullptr, 0, 0);

    {   // coalesced panel -> hT
        const int r = t >> 3;
        #pragma unroll
        for (int p = 0; p < 8; p++) {
            const int c16 = (t & 7) + p * 8;
            half8 h = *(const half8*)(lds + pswz(r, c16 * 16));
            *(half8*)(hT + (size_t)(row0 + r) * H_ + c16 * 8) = h;
        }
    }
}

// ---------------- fused branches: gather -> 3 layers -> out scatter ----------------
// block (d + 8*i): XCD-pinned so each XCD streams one domain's weights.
__global__ __launch_bounds__(512, 2) void branch_k(
    const f16* __restrict__ hT,
    const f16* __restrict__ U1p, const float* __restrict__ c1,
    const f16* __restrict__ U2p, const float* __restrict__ c2,
    const f16* __restrict__ U3p, const float* __restrict__ c3,
    const f16* __restrict__ Uop, const float* __restrict__ co,
    const int* __restrict__ offs, const int* __restrict__ cnt,
    const int* __restrict__ rowmap, float* __restrict__ out)
{
    extern __shared__ char lds[];
    const int d = blockIdx.x & 7, i = blockIdx.x >> 3;
    const int c = cnt[d];
    if (i * 64 >= c) return;
    const int row0 = offs[d] + i * 64;
    const int vend = offs[d] + c;
    const int t = threadIdx.x;
    const int lane = t & 63, wid = t >> 6;

    const half8* u1 = (const half8*)(U1p + (size_t)d * H_ * H_);
    const half8* u2 = (const half8*)(U2p + (size_t)d * H_ * H_);
    const half8* u3 = (const half8*)(U3p + (size_t)d * H_ * H_);
    const half8* uo = (const half8*)(Uop + (size_t)d * H_ * SDIM_);

    half8 b[4][4];
    #pragma unroll
    for (int s = 0; s < 3; s++)                    // preload flat steps 0,1,2 of layer 1
        #pragma unroll
        for (int n = 0; n < 4; n++)
            b[s][n] = u1[((wid * 4 + n) * 16 + s) * 64 + lane];

    // gather 64 trunk rows into swizzled panel (per-row fully coalesced)
    #pragma unroll
    for (int p = 0; p < 8; p++) {
        const int r   = p * 8 + wid;
        const int c16 = t & 63;
        const int src = rowmap[row0 + r];
        half8 h = *(const half8*)(hT + (size_t)src * H_ + c16 * 8);
        *(half8*)(lds + pswz(r, c16 * 16)) = h;
    }
    __syncthreads();

    // flat bases: 0, 16, 32, 48  ->  SB&3 = 0, 0, 0, 0
    layer_f<4, 4, 16, 4, 16, 0, true,  true >(lds, u1, u2, c1 + d * H_,    b, nullptr, nullptr, 0, 0);
    layer_f<4, 4, 16, 4, 16, 0, true,  true >(lds, u2, u3, c2 + d * H_,    b, nullptr, nullptr, 0, 0);
    layer_f<4, 4, 16, 1, 16, 0, true,  true >(lds, u3, uo, c3 + d * H_,    b, nullptr, nullptr, 0, 0);
    layer_f<4, 1, 16, 0, 16, 0, false, false>(lds, uo, uo, co + d * SDIM_, b, out, rowmap, row0, vend);
}

// ---------------- host ----------------
extern "C" void kernel_launch(void* const* d_in, const int* in_sizes, int n_in,
                              void* d_out, int out_size, void* d_ws, size_t ws_size,
                              hipStream_t stream)
{
    const float* z  = (const float*)d_in[0];
    const int*   y  = (const int*)d_in[1];
    const float* W0 = (const float*)d_in[2];
    const float* b0 = (const float*)d_in[3];
    const float* W1 = (const float*)d_in[4];
    const float* b1 = (const float*)d_in[5];
    const float* W2 = (const float*)d_in[6];
    const float* b2 = (const float*)d_in[7];
    const float* W3 = (const float*)d_in[8];
    const float* b3 = (const float*)d_in[9];
    const float* U1 = (const float*)d_in[10];
    const float* c1 = (const float*)d_in[11];
    const float* U2 = (const float*)d_in[12];
    const float* c2 = (const float*)d_in[13];
    const float* U3 = (const float*)d_in[14];
    const float* c3 = (const float*)d_in[15];
    const float* Uo = (const float*)d_in[16];
    const float* co = (const float*)d_in[17];
    float* out = (float*)d_out;

    char* p = (char*)d_ws;
    auto take = [&](size_t nbytes) { char* r = p; p += (nbytes + 255) & ~(size_t)255; return r; };
    int* cnt     = (int*)take(ND_ * 4);
    int* offs    = (int*)take((ND_ + 1) * 4);
    int* running = (int*)take(ND_ * 4);
    int* rowmap  = (int*)take((size_t)(B_ + 128) * 4);
    f16* W0t = (f16*)take((size_t)H_ * NZ_ * 2);
    f16* W1t = (f16*)take((size_t)H_ * H_ * 2);
    f16* W2t = (f16*)take((size_t)H_ * H_ * 2);
    f16* W3t = (f16*)take((size_t)H_ * H_ * 2);
    f16* U1t = (f16*)take((size_t)ND_ * H_ * H_ * 2);
    f16* U2t = (f16*)take((size_t)ND_ * H_ * H_ * 2);
    f16* U3t = (f16*)take((size_t)ND_ * H_ * H_ * 2);
    f16* Uot = (f16*)take((size_t)ND_ * SDIM_ * H_ * 2);
    f16* hT  = (f16*)take((size_t)B_ * H_ * 2);

    hipFuncSetAttribute((const void*)trunk_k,  hipFuncAttributeMaxDynamicSharedMemorySize, 64 * 1024);
    hipFuncSetAttribute((const void*)branch_k, hipFuncAttributeMaxDynamicSharedMemorySize, 64 * 1024);

    misc_k   <<<dim3(1), dim3(256), 0, stream>>>(cnt, rowmap);
    count_k  <<<dim3(B_ / 256), dim3(256), 0, stream>>>(y, cnt);
    prefix_k <<<dim3(1), dim3(64), 0, stream>>>(cnt, offs, running);
    scatter_k<<<dim3(B_ / 256), dim3(256), 0, stream>>>(y, running, rowmap);

    tr_k<<<dim3(TR_BLOCKS), dim3(256), 0, stream>>>(W0, W1, W2, W3, U1, U2, U3, Uo,
                                                    W0t, W1t, W2t, W3t, U1t, U2t, U3t, Uot);

    trunk_k<<<dim3(B_ / 64), dim3(512), 64 * 1024, stream>>>(
        z, W0t, b0, W1t, b1, W2t, b2, W3t, b3, hT);

    branch_k<<<dim3(8 * 48), dim3(512), 64 * 1024, stream>>>(
        hT, U1t, c1, U2t, c2, U3t, c3, Uot, co, offs, cnt, rowmap, out);
}

// Round 6
// 122.645 us; speedup vs baseline: 1.0597x; 1.0597x over previous
//
#include <hip/hip_runtime.h>

#define B_    16384
#define NZ_   64
#define ND_   8
#define SDIM_ 128
#define H_    512

typedef _Float16 f16;
typedef __attribute__((ext_vector_type(4))) _Float16 half4;
typedef __attribute__((ext_vector_type(8))) _Float16 half8;
typedef __attribute__((ext_vector_type(4))) float floatx4;

// swizzle byte-bits 4-6 with (row>>1)&7.  Residual SQ_LDS_BANK_CONFLICT ~2.1M
// is the inherent 2-lane/granule aliasing of wave64 ds_read_b128 (free, m136).
__device__ __forceinline__ int pswz(int row, int colbyte) {
    return (row * 1024 + colbyte) ^ (((row >> 1) & 7) << 4);
}

// ---------------- weight pack: [*,K,N] f32 -> fragment-tiled f16 ----------------
// packed ((nt*(K/32) + kt)*64 + lane)*8 + j == W[kt*32 + (lane>>4)*8 + j][nt*16 + (lane&15)]
__device__ __forceinline__ void tr_mat(float (*tb)[33], const float* __restrict__ s,
                                       f16* __restrict__ dd, int K, int N, int tl) {
    const int ntk = K >> 5;
    const int per = ntk * (N >> 5);
    const int bt  = tl / per;
    const int w   = tl - bt * per;
    s  += (size_t)bt * K * N;
    dd += (size_t)bt * K * N;
    const int k0 = (w % ntk) << 5, n0 = (w / ntk) << 5;
    const int tid = threadIdx.x;
    {
        const int nn = tid & 31, k4 = tid >> 5;
        #pragma unroll
        for (int p = 0; p < 4; p++)
            tb[k4 + p * 8][nn] = s[(size_t)(k0 + k4 + p * 8) * N + n0 + nn];
    }
    __syncthreads();
    {
        const int sub = tid >> 7, r = tid & 127;
        const int lane = r >> 1, jp = (r & 1) * 4;
        const int kb = lane >> 4, l15 = lane & 15;
        const size_t base = ((size_t)((n0 >> 4) + sub) * (K >> 5) + (k0 >> 5)) * 512
                          + lane * 8 + jp;
        half4 h;
        #pragma unroll
        for (int jj = 0; jj < 4; jj++)
            h[jj] = (f16)tb[kb * 8 + jp + jj][sub * 16 + l15];
        *(half4*)(dd + base) = h;
    }
}

__global__ __launch_bounds__(256) void tr_k(
    const float* W0, const float* W1, const float* W2, const float* W3,
    const float* U1, const float* U2, const float* U3, const float* Uo,
    f16* W0t, f16* W1t, f16* W2t, f16* W3t,
    f16* U1t, f16* U2t, f16* U3t, f16* Uot)
{
    __shared__ float tb[32][33];
    int tl = blockIdx.x;
    if (tl < 32)   { tr_mat(tb, W0, W0t, 64, 512, tl); return; }  tl -= 32;
    if (tl < 256)  { tr_mat(tb, W1, W1t, 512, 512, tl); return; } tl -= 256;
    if (tl < 256)  { tr_mat(tb, W2, W2t, 512, 512, tl); return; } tl -= 256;
    if (tl < 256)  { tr_mat(tb, W3, W3t, 512, 512, tl); return; } tl -= 256;
    if (tl < 2048) { tr_mat(tb, U1, U1t, 512, 512, tl); return; } tl -= 2048;
    if (tl < 2048) { tr_mat(tb, U2, U2t, 512, 512, tl); return; } tl -= 2048;
    if (tl < 2048) { tr_mat(tb, U3, U3t, 512, 512, tl); return; } tl -= 2048;
    tr_mat(tb, Uo, Uot, 512, 128, tl);
}
#define TR_BLOCKS 7456

// ---------------- domain sort ----------------
__global__ void misc_k(int* __restrict__ cnt, int* __restrict__ rowmap) {
    const int t = threadIdx.x;
    if (t < ND_) cnt[t] = 0;
    if (t < 128) rowmap[B_ + t] = 0;     // pad for last-domain tail tile
}

__global__ __launch_bounds__(256) void count_k(const int* __restrict__ y,
                                               int* __restrict__ cnt) {
    __shared__ int h[ND_];
    if (threadIdx.x < ND_) h[threadIdx.x] = 0;
    __syncthreads();
    atomicAdd(&h[y[blockIdx.x * 256 + threadIdx.x]], 1);   // grid covers B_ exactly
    __syncthreads();
    if (threadIdx.x < ND_) atomicAdd(&cnt[threadIdx.x], h[threadIdx.x]);
}

__global__ void prefix_k(const int* __restrict__ cnt, int* __restrict__ offs,
                         int* __restrict__ running) {
    if (threadIdx.x == 0) {
        int o = 0;
        offs[0] = 0;
        for (int d = 0; d < ND_; d++) { running[d] = o; o += cnt[d]; offs[d + 1] = o; }
    }
}

__global__ __launch_bounds__(256) void scatter_k(const int* __restrict__ y,
                                                 int* __restrict__ running,
                                                 int* __restrict__ rowmap) {
    __shared__ int h[ND_], base[ND_];
    if (threadIdx.x < ND_) h[threadIdx.x] = 0;
    __syncthreads();
    const int b = blockIdx.x * 256 + threadIdx.x;
    const int d = y[b];
    const int r = atomicAdd(&h[d], 1);
    __syncthreads();
    if (threadIdx.x < ND_) base[threadIdx.x] = atomicAdd(&running[threadIdx.x], h[threadIdx.x]);
    __syncthreads();
    rowmap[base[d] + r] = b;
}

// ---------------- one fused layer with rolling depth-3 cross-layer B prefetch ----------------
// Flat k-step counter across layers; ring b[4][4]; loads issued 3 steps ahead
// (incl. into the NEXT layer's weights wpn, hidden under epilogue+barrier).
// SB = flat-step base of this layer & 3.  NFN/KTN describe the next layer.
template<int MFRAG, int NFRAG, int KT, int NFN, int KTN, int SB, bool RELU, bool TOPANEL>
__device__ __forceinline__ void layer_f(
    char* lds, const half8* __restrict__ wp, const half8* __restrict__ wpn,
    const float* __restrict__ bias, half8 (&b)[4][4],
    float* __restrict__ outf, const int* __restrict__ rowmap, int row0, int vend)
{
    const int t = threadIdx.x;
    const int lane = t & 63, wid = t >> 6;
    const int l15 = lane & 15, kb = lane >> 4;

    int baseA[MFRAG];
    #pragma unroll
    for (int m = 0; m < MFRAG; m++)
        baseA[m] = (((m * 16 + l15) * 1024) + kb * 16) ^ (((l15 >> 1) & 7) << 4);

    half8 a[2][MFRAG];
    #pragma unroll
    for (int m = 0; m < MFRAG; m++) a[0][m] = *(const half8*)(lds + baseA[m]);

    floatx4 acc[MFRAG][NFRAG] = {};

    #pragma unroll
    for (int kt = 0; kt < KT; kt++) {
        const int cur = kt & 1;
        if (kt + 1 < KT) {                         // A prefetch, 1 step ahead
            #pragma unroll
            for (int m = 0; m < MFRAG; m++)
                a[cur ^ 1][m] = *(const half8*)(lds + (baseA[m] ^ ((kt + 1) << 6)));
        }
        if (kt + 3 < KT) {                         // B prefetch, 3 steps ahead
            #pragma unroll
            for (int n = 0; n < NFRAG; n++)
                b[(SB + kt + 3) & 3][n] = wp[((wid * NFRAG + n) * KT + kt + 3) * 64 + lane];
        } else if constexpr (NFN > 0) {            // cross into next layer (steps 0..2 of it)
            const int s2 = kt + 3 - KT;
            #pragma unroll
            for (int n = 0; n < NFN; n++)
                b[(SB + kt + 3) & 3][n] = wpn[((wid * NFN + n) * KTN + s2) * 64 + lane];
        }
        __builtin_amdgcn_s_setprio(1);
        #pragma unroll
        for (int m = 0; m < MFRAG; m++)
            #pragma unroll
            for (int n = 0; n < NFRAG; n++)
                acc[m][n] = __builtin_amdgcn_mfma_f32_16x16x32_f16(
                    a[cur][m], b[(SB + kt) & 3][n], acc[m][n], 0, 0, 0);
        __builtin_amdgcn_s_setprio(0);
    }

    __syncthreads();   // all waves done reading panel

    #pragma unroll
    for (int n = 0; n < NFRAG; n++) {
        const int col = wid * (NFRAG * 16) + n * 16 + l15;
        const float bb = bias[col];
        #pragma unroll
        for (int m = 0; m < MFRAG; m++) {
            #pragma unroll
            for (int e = 0; e < 4; e++) {
                const int row = m * 16 + kb * 4 + e;
                float v = acc[m][n][e] + bb;
                if constexpr (RELU) v = fmaxf(v, 0.0f);
                if constexpr (TOPANEL) {
                    *(f16*)(lds + pswz(row, col * 2)) = (f16)v;
                } else {
                    const int pr = row0 + row;
                    if (pr < vend) outf[(size_t)rowmap[pr] * SDIM_ + col] = v;
                }
            }
        }
    }
    if constexpr (TOPANEL) __syncthreads();   // panel is next layer's input
}

// ---------------- fused trunk: z -> 4 layers -> hT ----------------
__global__ __launch_bounds__(512, 2) void trunk_k(
    const float* __restrict__ z,
    const f16* __restrict__ W0p, const float* __restrict__ b0,
    const f16* __restrict__ W1p, const float* __restrict__ b1,
    const f16* __restrict__ W2p, const float* __restrict__ b2,
    const f16* __restrict__ W3p, const float* __restrict__ b3,
    f16* __restrict__ hT)
{
    extern __shared__ char lds[];
    const int t = threadIdx.x;
    const int row0 = blockIdx.x * 64;
    const int lane = t & 63, wid = t >> 6;

    const half8* w0 = (const half8*)W0p;
    const half8* w1 = (const half8*)W1p;
    const half8* w2 = (const half8*)W2p;
    const half8* w3 = (const half8*)W3p;

    half8 b[4][4];
    #pragma unroll
    for (int n = 0; n < 4; n++) {                  // flat steps 0,1 (w0 KT=2), 2 (w1 s0)
        b[0][n] = w0[((wid * 4 + n) * 2 + 0) * 64 + lane];
        b[1][n] = w0[((wid * 4 + n) * 2 + 1) * 64 + lane];
        b[2][n] = w1[((wid * 4 + n) * 16 + 0) * 64 + lane];
    }

    {   // fill panel with z rows (f32 -> f16), swizzled
        const int r = t >> 3, c = (t & 7) * 8;
        const float4 v0 = *(const float4*)(z + (size_t)(row0 + r) * NZ_ + c);
        const float4 v1 = *(const float4*)(z + (size_t)(row0 + r) * NZ_ + c + 4);
        half8 h = { (f16)v0.x, (f16)v0.y, (f16)v0.z, (f16)v0.w,
                    (f16)v1.x, (f16)v1.y, (f16)v1.z, (f16)v1.w };
        *(half8*)(lds + pswz(r, c * 2)) = h;
    }
    __syncthreads();

    // flat bases: 0, 2, 18, 34  ->  SB&3 = 0, 2, 2, 2
    layer_f<4, 4, 2,  4, 16, 0, true, true>(lds, w0, w1, b0, b, nullptr, nullptr, 0, 0);
    layer_f<4, 4, 16, 4, 16, 2, true, true>(lds, w1, w2, b1, b, nullptr, nullptr, 0, 0);
    layer_f<4, 4, 16, 4, 16, 2, true, true>(lds, w2, w3, b2, b, nullptr, nullptr, 0, 0);
    layer_f<4, 4, 16, 0, 16, 2, true, true>(lds, w3, w3, b3, b, nullptr, nullptr, 0, 0);

    {   // coalesced panel -> hT
        const int r = t >> 3;
        #pragma unroll
        for (int p = 0; p < 8; p++) {
            const int c16 = (t & 7) + p * 8;
            half8 h = *(const half8*)(lds + pswz(r, c16 * 16));
            *(half8*)(hT + (size_t)(row0 + r) * H_ + c16 * 8) = h;
        }
    }
}

// ---------------- fused branches: gather -> 3 layers -> out scatter ----------------
// block (d + 8*i): XCD-pinned so each XCD streams one domain's weights.
// 80-row tiles, grid 8*30 = 240 <= 256 CUs -> every work block gets its own CU.
__global__ __launch_bounds__(512, 2) void branch_k(
    const f16* __restrict__ hT,
    const f16* __restrict__ U1p, const float* __restrict__ c1,
    const f16* __restrict__ U2p, const float* __restrict__ c2,
    const f16* __restrict__ U3p, const float* __restrict__ c3,
    const f16* __restrict__ Uop, const float* __restrict__ co,
    const int* __restrict__ offs, const int* __restrict__ cnt,
    const int* __restrict__ rowmap, float* __restrict__ out)
{
    extern __shared__ char lds[];
    const int d = blockIdx.x & 7, i = blockIdx.x >> 3;
    const int c = cnt[d];
    if (i * 80 >= c) return;
    const int row0 = offs[d] + i * 80;
    const int vend = offs[d] + c;
    const int t = threadIdx.x;
    const int lane = t & 63, wid = t >> 6;

    const half8* u1 = (const half8*)(U1p + (size_t)d * H_ * H_);
    const half8* u2 = (const half8*)(U2p + (size_t)d * H_ * H_);
    const half8* u3 = (const half8*)(U3p + (size_t)d * H_ * H_);
    const half8* uo = (const half8*)(Uop + (size_t)d * H_ * SDIM_);

    half8 b[4][4];
    #pragma unroll
    for (int s = 0; s < 3; s++)                    // preload flat steps 0,1,2 of layer 1
        #pragma unroll
        for (int n = 0; n < 4; n++)
            b[s][n] = u1[((wid * 4 + n) * 16 + s) * 64 + lane];

    // gather 80 trunk rows into swizzled panel (per-row fully coalesced)
    #pragma unroll
    for (int p = 0; p < 10; p++) {
        const int r   = p * 8 + wid;
        const int c16 = t & 63;
        const int src = rowmap[row0 + r];
        half8 h = *(const half8*)(hT + (size_t)src * H_ + c16 * 8);
        *(half8*)(lds + pswz(r, c16 * 16)) = h;
    }
    __syncthreads();

    // flat bases: 0, 16, 32, 48  ->  SB&3 = 0, 0, 0, 0
    layer_f<5, 4, 16, 4, 16, 0, true,  true >(lds, u1, u2, c1 + d * H_,    b, nullptr, nullptr, 0, 0);
    layer_f<5, 4, 16, 4, 16, 0, true,  true >(lds, u2, u3, c2 + d * H_,    b, nullptr, nullptr, 0, 0);
    layer_f<5, 4, 16, 1, 16, 0, true,  true >(lds, u3, uo, c3 + d * H_,    b, nullptr, nullptr, 0, 0);
    layer_f<5, 1, 16, 0, 16, 0, false, false>(lds, uo, uo, co + d * SDIM_, b, out, rowmap, row0, vend);
}

// ---------------- host ----------------
extern "C" void kernel_launch(void* const* d_in, const int* in_sizes, int n_in,
                              void* d_out, int out_size, void* d_ws, size_t ws_size,
                              hipStream_t stream)
{
    const float* z  = (const float*)d_in[0];
    const int*   y  = (const int*)d_in[1];
    const float* W0 = (const float*)d_in[2];
    const float* b0 = (const float*)d_in[3];
    const float* W1 = (const float*)d_in[4];
    const float* b1 = (const float*)d_in[5];
    const float* W2 = (const float*)d_in[6];
    const float* b2 = (const float*)d_in[7];
    const float* W3 = (const float*)d_in[8];
    const float* b3 = (const float*)d_in[9];
    const float* U1 = (const float*)d_in[10];
    const float* c1 = (const float*)d_in[11];
    const float* U2 = (const float*)d_in[12];
    const float* c2 = (const float*)d_in[13];
    const float* U3 = (const float*)d_in[14];
    const float* c3 = (const float*)d_in[15];
    const float* Uo = (const float*)d_in[16];
    const float* co = (const float*)d_in[17];
    float* out = (float*)d_out;

    char* p = (char*)d_ws;
    auto take = [&](size_t nbytes) { char* r = p; p += (nbytes + 255) & ~(size_t)255; return r; };
    int* cnt     = (int*)take(ND_ * 4);
    int* offs    = (int*)take((ND_ + 1) * 4);
    int* running = (int*)take(ND_ * 4);
    int* rowmap  = (int*)take((size_t)(B_ + 128) * 4);
    f16* W0t = (f16*)take((size_t)H_ * NZ_ * 2);
    f16* W1t = (f16*)take((size_t)H_ * H_ * 2);
    f16* W2t = (f16*)take((size_t)H_ * H_ * 2);
    f16* W3t = (f16*)take((size_t)H_ * H_ * 2);
    f16* U1t = (f16*)take((size_t)ND_ * H_ * H_ * 2);
    f16* U2t = (f16*)take((size_t)ND_ * H_ * H_ * 2);
    f16* U3t = (f16*)take((size_t)ND_ * H_ * H_ * 2);
    f16* Uot = (f16*)take((size_t)ND_ * SDIM_ * H_ * 2);
    f16* hT  = (f16*)take((size_t)B_ * H_ * 2);

    hipFuncSetAttribute((const void*)trunk_k,  hipFuncAttributeMaxDynamicSharedMemorySize, 64 * 1024);
    hipFuncSetAttribute((const void*)branch_k, hipFuncAttributeMaxDynamicSharedMemorySize, 80 * 1024);

    misc_k   <<<dim3(1), dim3(256), 0, stream>>>(cnt, rowmap);
    count_k  <<<dim3(B_ / 256), dim3(256), 0, stream>>>(y, cnt);
    prefix_k <<<dim3(1), dim3(64), 0, stream>>>(cnt, offs, running);
    scatter_k<<<dim3(B_ / 256), dim3(256), 0, stream>>>(y, running, rowmap);

    tr_k<<<dim3(TR_BLOCKS), dim3(256), 0, stream>>>(W0, W1, W2, W3, U1, U2, U3, Uo,
                                                    W0t, W1t, W2t, W3t, U1t, U2t, U3t, Uot);

    trunk_k<<<dim3(B_ / 64), dim3(512), 64 * 1024, stream>>>(
        z, W0t, b0, W1t, b1, W2t, b2, W3t, b3, hT);

    branch_k<<<dim3(8 * 30), dim3(512), 80 * 1024, stream>>>(
        hT, U1t, c1, U2t, c2, U3t, c3, Uot, co, offs, cnt, rowmap, out);
}